// Round 2
// baseline (162.252 us; speedup 1.0000x reference)
//
#include <hip/hip_runtime.h>

// Problem constants (match reference)
#define A_   5
#define C_   80
#define BB   16
#define HH   64
#define WW   64
#define NN   50
#define CH   (5 + C_)      // 85 channels per anchor
#define HW   (HH * WW)     // 4096
#define STRIDE_F 16.0f

// Single fused kernel: box staging (LDS), decode, IoU argmax, losses.
// One block = one (b, a, 4 rows of h). 256 threads: lane (tid&63) = w, (tid>>6) = sub-row.
// Each wave handles one full row of W=64 -> channel loads are perfectly coalesced.
__global__ __launch_bounds__(256)
void region_loss_kernel(const float* __restrict__ out4d,    // (B, A*85, 64, 64)
                        const float* __restrict__ target,   // (B, 50, 5): cls, cx, cy, w, h
                        const float* __restrict__ anchors,  // (5, 2)
                        float* __restrict__ loss)
{
    __shared__ float g_x1[NN], g_y1[NN], g_x2[NN], g_y2[NN], g_area[NN];
    __shared__ float g_cx[NN], g_cy[NN], g_w[NN], g_h[NN], g_cls[NN];
    __shared__ float wave_sum[4];

    const int bid = blockIdx.x;
    const int h4  = bid & 15;            // H/4 = 16 blocks of rows
    const int a   = (bid >> 4) % A_;
    const int b   = bid / (A_ * 16);

    const int tid = threadIdx.x;
    const int w   = tid & 63;
    const int h   = (h4 << 2) + (tid >> 6);

    // Channel base for this (b, a, h, w); channel stride = HW floats.
    const float* base = out4d + (size_t)(b * (A_ * CH) + a * CH) * HW + h * WW + w;

    // Issue the 5 coalesced channel loads FIRST so their HBM latency overlaps
    // the box staging below (no dependence until after the barrier).
    const float x0 = base[0 * HW];
    const float x1 = base[1 * HW];
    const float x2 = base[2 * HW];
    const float x3 = base[3 * HW];
    const float cf = base[4 * HW];

    // Stage GT boxes for this batch into LDS, pre-expanded to corners + area.
    if (tid < NN) {
        const float* t = target + ((size_t)b * NN + tid) * 5;
        float cls = t[0], cx = t[1], cy = t[2], gw = t[3], gh = t[4];
        g_cls[tid]  = cls;
        g_cx[tid]   = cx;  g_cy[tid] = cy;  g_w[tid] = gw;  g_h[tid] = gh;
        g_x1[tid]   = cx - gw * 0.5f;  g_y1[tid] = cy - gh * 0.5f;
        g_x2[tid]   = cx + gw * 0.5f;  g_y2[tid] = cy + gh * 0.5f;
        g_area[tid] = gw * gh + 1e-6f;
    }
    __syncthreads();

    const float aw = anchors[a * 2 + 0];   // block-uniform -> scalar load
    const float ah = anchors[a * 2 + 1];

    // Decode predicted box
    const float px = (1.0f / (1.0f + __expf(-x0)) + (float)w) * STRIDE_F;
    const float py = (1.0f / (1.0f + __expf(-x1)) + (float)h) * STRIDE_F;
    const float pw = __expf(x2) * aw;
    const float ph = __expf(x3) * ah;
    const float px1 = px - pw * 0.5f, py1 = py - ph * 0.5f;
    const float px2 = px + pw * 0.5f, py2 = py + ph * 0.5f;
    const float parea = pw * ph;

    // Argmax IoU over 50 GT boxes; cross-mult instead of divide.
    // LDS broadcast reads (same address across lanes) are conflict-free.
    float best_inter = 0.0f, best_union = 1.0f;
    int best_n = 0;
    #pragma unroll 10
    for (int n = 0; n < NN; ++n) {
        float ix1 = fmaxf(g_x1[n], px1);
        float iy1 = fmaxf(g_y1[n], py1);
        float ix2 = fminf(g_x2[n], px2);
        float iy2 = fminf(g_y2[n], py2);
        float iw  = fmaxf(ix2 - ix1, 0.0f);
        float ih  = fmaxf(iy2 - iy1, 0.0f);
        float inter = iw * ih;
        float uni   = (g_area[n] + parea) - inter;   // +1e-6 folded into g_area
        if (inter * best_union > best_inter * uni) {
            best_inter = inter; best_union = uni; best_n = n;
        }
    }
    const bool mask = best_inter > 0.6f * best_union;

    float local = cf * cf;                // conf_mask=1, tconf=0 (unmasked)
    if (mask) {
        // Divergent branch: exec-masked loads fetch only masked lanes' lines;
        // s_cbranch_execz skips the whole body for clean waves.
        const float d0 = x0 - g_cx[best_n];
        const float d1 = x1 - g_cy[best_n];
        const float d2 = x2 - g_w[best_n];
        const float d3 = x3 - g_h[best_n];
        const float cd = 5.0f * cf - 5.0f;   // conf_mask=5, tconf=1

        // Class NLL: two-pass max-subtracted logsumexp.
        // Pass 1: max with 4 independent accumulators (breaks the dep chain).
        float m0 = -1e30f, m1 = -1e30f, m2 = -1e30f, m3 = -1e30f;
        #pragma unroll 5
        for (int c = 0; c < C_; c += 4) {
            m0 = fmaxf(m0, base[(5 + c) * HW]);
            m1 = fmaxf(m1, base[(6 + c) * HW]);
            m2 = fmaxf(m2, base[(7 + c) * HW]);
            m3 = fmaxf(m3, base[(8 + c) * HW]);
        }
        const float m = fmaxf(fmaxf(m0, m1), fmaxf(m2, m3));

        // Pass 2: sum of exp (reloads hit L1/L2), 2 independent accumulators.
        float s0 = 0.0f, s1 = 0.0f;
        #pragma unroll 10
        for (int c = 0; c < C_; c += 2) {
            s0 += __expf(base[(5 + c) * HW] - m);
            s1 += __expf(base[(6 + c) * HW] - m);
        }
        const int   tcls = (int)g_cls[best_n];
        const float xt   = base[(5 + tcls) * HW];   // direct gather
        local = d0*d0 + d1*d1 + d2*d2 + d3*d3 + cd*cd
              + (m + __logf(s0 + s1) - xt);         // nll = lse - x[tcls]
    }

    // Wave (64-lane) shuffle reduction, then cross-wave via LDS, one atomic per block.
    for (int off = 32; off > 0; off >>= 1)
        local += __shfl_down(local, off);
    if ((tid & 63) == 0) wave_sum[tid >> 6] = local;
    __syncthreads();
    if (tid == 0)
        atomicAdd(loss, wave_sum[0] + wave_sum[1] + wave_sum[2] + wave_sum[3]);
}

extern "C" void kernel_launch(void* const* d_in, const int* in_sizes, int n_in,
                              void* d_out, int out_size, void* d_ws, size_t ws_size,
                              hipStream_t stream) {
    const float* output  = (const float*)d_in[0];
    const float* target  = (const float*)d_in[1];
    const float* anchors = (const float*)d_in[2];
    float* loss = (float*)d_out;

    // Zero the scalar loss with a graph-capturable memset node (no prep kernel).
    hipMemsetAsync(loss, 0, sizeof(float), stream);

    const int grid = BB * A_ * (HH / 4);   // 1280 blocks
    region_loss_kernel<<<grid, 256, 0, stream>>>(output, target, anchors, loss);
}